// Round 5
// baseline (1365.901 us; speedup 1.0000x reference)
//
#include <hip/hip_runtime.h>

// GLM MLA fused pipeline, round 5.
// r4 post-mortem: GEMM1 961 TF (8-phase+swizzle verified: conflicts 5e7->0).
// r5 change: attention rewritten as fully wave-independent (no barriers, no
// K/V LDS staging — K/V streamed from L2 as contiguous half8; per-wave sP
// bounce only; longest-first slot mapping). GEMMs/converts unchanged.

typedef __attribute__((ext_vector_type(4))) float f32x4;
typedef _Float16 half8 __attribute__((ext_vector_type(8)));
typedef _Float16 half4 __attribute__((ext_vector_type(4)));

#define AS3(p) ((__attribute__((address_space(3))) void*)(p))
#define AS1(p) ((__attribute__((address_space(1))) void*)(void*)(p))

// ---------------- hs f32 -> f16 ----------------
__global__ __launch_bounds__(256) void k_convert(const float* __restrict__ src,
                                                 _Float16* __restrict__ dst) {
  int i = (blockIdx.x * 256 + threadIdx.x) * 8;
  float4 a = *(const float4*)(src + i);
  float4 b = *(const float4*)(src + i + 4);
  half8 v = { (_Float16)a.x, (_Float16)a.y, (_Float16)a.z, (_Float16)a.w,
              (_Float16)b.x, (_Float16)b.y, (_Float16)b.z, (_Float16)b.w };
  *(half8*)(dst + i) = v;
}

// ------- transpose-convert wq(nope cols)+wkv -> wqkvT [12288][4096] f16 -------
__global__ __launch_bounds__(256) void k_tc_qkv(const float* __restrict__ wq,
                                                const float* __restrict__ wkv,
                                                _Float16* __restrict__ out) {
  __shared__ __align__(16) _Float16 t[64][72];
  int k0 = blockIdx.x * 64;
  int c0 = blockIdx.y * 64;
  int tid = threadIdx.x;
  int rl = tid >> 4;
  int cl4 = (tid & 15) << 2;
  int c = c0 + cl4;
#pragma unroll
  for (int i = 0; i < 4; ++i) {
    int r = k0 + rl + i * 16;
    const float* sp;
    if (c0 < 4096) sp = wq + (size_t)r * 6144 + ((c >> 7) * 192 + (c & 127));
    else           sp = wkv + (size_t)r * 8256 + (c - 4096);
    float4 v = *(const float4*)sp;
    t[cl4 + 0][rl + i * 16] = (_Float16)v.x;
    t[cl4 + 1][rl + i * 16] = (_Float16)v.y;
    t[cl4 + 2][rl + i * 16] = (_Float16)v.z;
    t[cl4 + 3][rl + i * 16] = (_Float16)v.w;
  }
  __syncthreads();
  int r4 = (tid & 15) << 2;
#pragma unroll
  for (int i = 0; i < 4; ++i) {
    int cl = (tid >> 4) + i * 16;
    half4 p = { t[cl][r4], t[cl][r4 + 1], t[cl][r4 + 2], t[cl][r4 + 3] };
    *(half4*)(out + (size_t)(c0 + cl) * 4096 + k0 + r4) = p;
  }
}

// ------- transpose-convert wo -> woT [4096][4096] f16 -------
__global__ __launch_bounds__(256) void k_tc_wo(const float* __restrict__ wo,
                                               _Float16* __restrict__ out) {
  __shared__ __align__(16) _Float16 t[64][72];
  int k0 = blockIdx.x * 64;
  int c0 = blockIdx.y * 64;
  int tid = threadIdx.x;
  int rl = tid >> 4;
  int cl4 = (tid & 15) << 2;
#pragma unroll
  for (int i = 0; i < 4; ++i) {
    int r = k0 + rl + i * 16;
    float4 v = *(const float4*)(wo + (size_t)r * 4096 + c0 + cl4);
    t[cl4 + 0][rl + i * 16] = (_Float16)v.x;
    t[cl4 + 1][rl + i * 16] = (_Float16)v.y;
    t[cl4 + 2][rl + i * 16] = (_Float16)v.z;
    t[cl4 + 3][rl + i * 16] = (_Float16)v.w;
  }
  __syncthreads();
  int r4 = (tid & 15) << 2;
#pragma unroll
  for (int i = 0; i < 4; ++i) {
    int cl = (tid >> 4) + i * 16;
    half4 p = { t[cl][r4], t[cl][r4 + 1], t[cl][r4 + 2], t[cl][r4 + 3] };
    *(half4*)(out + (size_t)(c0 + cl) * 4096 + k0 + r4) = p;
  }
}

// ============ 256^2 8-phase GEMM (unchanged from r4) ============
#define A_OFF(d, h) ((d) * 32768 + (h) * 16384)
#define B_OFF(d, h) (65536 + (d) * 32768 + (h) * 16384)

#define STAGE(gbase, ldsoff, ktb)                                              \
  do {                                                                         \
    _Pragma("unroll") for (int i_ = 0; i_ < 2; ++i_) {                         \
      int c_ = w * 2 + i_;                                                     \
      int row_ = c_ * 16 + (lane >> 2);                                        \
      int ss_ = (lane & 3) ^ ((lane >> 3) & 3);                                \
      __builtin_amdgcn_global_load_lds(                                        \
          AS1((gbase) + (size_t)row_ * ldb + (ktb) + ss_ * 16),                \
          AS3(lds + (ldsoff) + c_ * 1024), 16, 0, 0);                          \
    }                                                                          \
  } while (0)

#define LDA(dst, d, ks, fm)                                                    \
  do {                                                                         \
    int r_ = wr * 128 + (fm) * 16 + (lane & 15);                               \
    int sl_ = (lane >> 4) ^ ((r_ >> 1) & 3);                                   \
    dst = *(const half8*)(lds + (d) * 32768 + (ks) * 16384 + r_ * 64 +         \
                          sl_ * 16);                                           \
  } while (0)

#define LDB(dst, d, ks, fn)                                                    \
  do {                                                                         \
    int r_ = wc * 64 + (fn) * 16 + (lane & 15);                                \
    int sl_ = (lane >> 4) ^ ((r_ >> 1) & 3);                                   \
    dst = *(const half8*)(lds + 65536 + (d) * 32768 + (ks) * 16384 +           \
                          r_ * 64 + sl_ * 16);                                 \
  } while (0)

#define BARRIER()                                                              \
  do {                                                                         \
    asm volatile("" ::: "memory");                                             \
    __builtin_amdgcn_s_barrier();                                              \
    asm volatile("" ::: "memory");                                             \
  } while (0)

#define MFMA16(mh)                                                             \
  do {                                                                         \
    __builtin_amdgcn_s_setprio(1);                                             \
    _Pragma("unroll") for (int mi_ = 0; mi_ < 4; ++mi_)                        \
        _Pragma("unroll") for (int ni_ = 0; ni_ < 4; ++ni_)                    \
            acc[(mh) * 4 + mi_][ni_] = __builtin_amdgcn_mfma_f32_16x16x32_f16( \
                af[mi_], bfr[ni_], acc[(mh) * 4 + mi_][ni_], 0, 0, 0);         \
    __builtin_amdgcn_s_setprio(0);                                             \
  } while (0)

__global__ __launch_bounds__(512, 2) void k_gemm256(
    const _Float16* __restrict__ A, const _Float16* __restrict__ Bt,
    void* __restrict__ outp, int M, int N, int K, int mode, int ntn, int nblk) {
  extern __shared__ __align__(16) char lds[];
  int tid = threadIdx.x, lane = tid & 63, w = tid >> 6;
  int wr = w >> 2, wc = w & 3;
  int bid = blockIdx.x;
  int sid = (bid & 7) * (nblk >> 3) + (bid >> 3);
  int mt = sid / ntn, nt = sid % ntn;
  int m0 = mt * 256, n0 = nt * 256;

  const char* Ab = (const char*)(A + (size_t)m0 * K);
  const char* Bb = (const char*)(Bt + (size_t)n0 * K);
  size_t ldb = (size_t)K * 2;

  f32x4 acc[8][4];
#pragma unroll
  for (int i = 0; i < 8; ++i)
#pragma unroll
    for (int j = 0; j < 4; ++j) acc[i][j] = (f32x4){0.f, 0.f, 0.f, 0.f};
  half8 af[4], bfr[4];

  int NT = K >> 6;
  STAGE(Ab, A_OFF(0, 0), 0);
  STAGE(Bb, B_OFF(0, 0), 0);
  STAGE(Ab, A_OFF(0, 1), 64);
  STAGE(Bb, B_OFF(0, 1), 64);
  STAGE(Ab, A_OFF(1, 0), 128);
  STAGE(Bb, B_OFF(1, 0), 128);
  asm volatile("s_waitcnt vmcnt(4)" ::: "memory");
  BARRIER();

  for (int k = 0; k < NT; ++k) {
    int d = k & 1, dn = d ^ 1;
    int ktb1 = (k + 1) << 7, ktb2 = (k + 2) << 7;
    bool s1 = (k + 1 < NT), s2 = (k + 2 < NT);
    LDB(bfr[0], d, 0, 0); LDB(bfr[1], d, 0, 1);
    LDB(bfr[2], d, 0, 2); LDB(bfr[3], d, 0, 3);
    LDA(af[0], d, 0, 0); LDA(af[1], d, 0, 1);
    LDA(af[2], d, 0, 2); LDA(af[3], d, 0, 3);
    if (s1) STAGE(Ab, A_OFF(dn, 1), ktb1 + 64);
    BARRIER();
    MFMA16(0);
    BARRIER();
    LDA(af[0], d, 0, 4); LDA(af[1], d, 0, 5);
    LDA(af[2], d, 0, 6); LDA(af[3], d, 0, 7);
    if (s1) STAGE(Bb, B_OFF(dn, 1), ktb1 + 64);
    BARRIER();
    MFMA16(1);
    BARRIER();
    LDB(bfr[0], d, 1, 0); LDB(bfr[1], d, 1, 1);
    LDB(bfr[2], d, 1, 2); LDB(bfr[3], d, 1, 3);
    LDA(af[0], d, 1, 0); LDA(af[1], d, 1, 1);
    LDA(af[2], d, 1, 2); LDA(af[3], d, 1, 3);
    if (s2) STAGE(Ab, A_OFF(d, 0), ktb2);
    BARRIER();
    MFMA16(0);
    BARRIER();
    LDA(af[0], d, 1, 4); LDA(af[1], d, 1, 5);
    LDA(af[2], d, 1, 6); LDA(af[3], d, 1, 7);
    if (s2) {
      STAGE(Bb, B_OFF(d, 0), ktb2);
      asm volatile("s_waitcnt vmcnt(4)" ::: "memory");
    } else {
      asm volatile("s_waitcnt vmcnt(0)" ::: "memory");
    }
    BARRIER();
    MFMA16(1);
    BARRIER();
  }

  if (mode == 2) {
    float* O = (float*)outp;
#pragma unroll
    for (int fm = 0; fm < 8; ++fm)
#pragma unroll
      for (int j = 0; j < 4; ++j) {
        int r = m0 + wr * 128 + fm * 16 + ((lane >> 4) << 2) + j;
        float* op = O + (size_t)r * N + n0 + wc * 64 + (lane & 15);
#pragma unroll
        for (int ni = 0; ni < 4; ++ni) op[ni * 16] = acc[fm][ni][j];
      }
  } else {
    _Float16* Q = (_Float16*)outp;
    _Float16* Kk = Q + 16777216;
    _Float16* Vt = Q + 33554432;
    int cb0 = n0 + wc * 64;
    int seg = cb0 >> 12;
    int h = (cb0 >> 7) & 31;
    int dbase = cb0 & 127;
    if (seg < 2) {
      _Float16* Obuf = (seg == 0) ? Q : Kk;
#pragma unroll
      for (int fm = 0; fm < 8; ++fm) {
        int t0 = m0 + wr * 128 + fm * 16 + ((lane >> 4) << 2);
        int bb = t0 >> 10, s0 = t0 & 1023;
        size_t base = ((size_t)bb * 32 + h) * 1024;
#pragma unroll
        for (int j = 0; j < 4; ++j)
#pragma unroll
          for (int ni = 0; ni < 4; ++ni)
            Obuf[(base + s0 + j) * 128 + dbase + ni * 16 + (lane & 15)] =
                (_Float16)acc[fm][ni][j];
      }
    } else {
#pragma unroll
      for (int fm = 0; fm < 8; ++fm) {
        int t0 = m0 + wr * 128 + fm * 16 + ((lane >> 4) << 2);
        int bb = t0 >> 10, s0 = t0 & 1023;
#pragma unroll
        for (int ni = 0; ni < 4; ++ni) {
          int dd = dbase + ni * 16 + (lane & 15);
          half4 p = { (_Float16)acc[fm][ni][0], (_Float16)acc[fm][ni][1],
                      (_Float16)acc[fm][ni][2], (_Float16)acc[fm][ni][3] };
          *(half4*)(Vt + (((size_t)bb * 32 + h) * 128 + dd) * 1024 + s0) = p;
        }
      }
    }
  }
}

// ---------------- causal flash attention, wave-independent ----------------
// Q,K: [B,H,S,128] f16 ; Vt: [B,H,128,S] f16 ; out: [B*S][H*128] f16
// One wave = 16 q-rows. No barriers; K/V streamed from L2 as half8;
// per-wave sP bounce for the P re-fragmentation. Longest-qt-first slots.
__global__ __launch_bounds__(256) void k_attn(const _Float16* __restrict__ Qb,
                                              const _Float16* __restrict__ Kb,
                                              const _Float16* __restrict__ Vtb,
                                              _Float16* __restrict__ outp) {
  __shared__ __align__(16) _Float16 sP[4][16][72];
  const float SCL = 0.10411834905624762f;  // 192^-0.5 * log2(e)
  int tid = threadIdx.x;
  int lane = tid & 63;
  int w = tid >> 6;
  int gslot = blockIdx.x * 4 + w;   // 0..8191
  int bh = gslot >> 6;              // 0..127 (same for all 4 waves of a block)
  int slot = gslot & 63;
  int qt = 63 - slot;               // longest-first
  int q0 = qt * 16;
  int b = bh >> 5, h = bh & 31;
  const _Float16* Qp = Qb + (size_t)bh * (1024 * 128);
  const _Float16* Kp = Kb + (size_t)bh * (1024 * 128);
  const _Float16* Vp = Vtb + (size_t)bh * (128 * 1024);

  half8 aQ[4];
  {
    const _Float16* qr = Qp + (size_t)(q0 + (lane & 15)) * 128 + ((lane >> 4) << 3);
#pragma unroll
    for (int ks = 0; ks < 4; ++ks) aQ[ks] = *(const half8*)(qr + ks * 32);
  }
  f32x4 accO[8];
#pragma unroll
  for (int g = 0; g < 8; ++g) accO[g] = (f32x4){0.f, 0.f, 0.f, 0.f};
  float m_r[4] = { -__builtin_inff(), -__builtin_inff(), -__builtin_inff(), -__builtin_inff() };
  float l_r[4] = { 0.f, 0.f, 0.f, 0.f };

  int ntile = (qt >> 2) + 1;        // ceil((q0+16)/64)
  int qrb = q0 + ((lane >> 4) << 2);
  // per-lane K/V base slices
  const _Float16* Kl = Kp + (size_t)(lane & 15) * 128 + ((lane >> 4) << 3);
  const _Float16* Vl = Vp + (size_t)(lane & 15) * 1024 + ((lane >> 4) << 3);

  for (int kt = 0; kt < ntile; ++kt) {
    int kv0 = kt * 64;
    // QK^T : 16 q-rows x 64 kv, K streamed from global (contiguous half8)
    f32x4 sc[4];
#pragma unroll
    for (int g = 0; g < 4; ++g) {
      const _Float16* kb = Kl + (size_t)(kv0 + g * 16) * 128;
      f32x4 c = (f32x4){0.f, 0.f, 0.f, 0.f};
#pragma unroll
      for (int ks = 0; ks < 4; ++ks) {
        half8 bk = *(const half8*)(kb + ks * 32);
        c = __builtin_amdgcn_mfma_f32_16x16x32_f16(aQ[ks], bk, c, 0, 0, 0);
      }
      sc[g] = c;
    }
    // mask + online softmax (log2 domain)
    bool diag = (kt == ntile - 1);
    float sv[4][4];  // [j][g]
#pragma unroll
    for (int g = 0; g < 4; ++g) {
      int kvc = kv0 + g * 16 + (lane & 15);
#pragma unroll
      for (int j = 0; j < 4; ++j) {
        float s = sc[g][j] * SCL;
        if (diag && kvc > qrb + j) s = -__builtin_inff();
        sv[j][g] = s;
      }
    }
#pragma unroll
    for (int j = 0; j < 4; ++j) {
      float mx = fmaxf(fmaxf(sv[j][0], sv[j][1]), fmaxf(sv[j][2], sv[j][3]));
      mx = fmaxf(mx, __shfl_xor(mx, 1));
      mx = fmaxf(mx, __shfl_xor(mx, 2));
      mx = fmaxf(mx, __shfl_xor(mx, 4));
      mx = fmaxf(mx, __shfl_xor(mx, 8));
      float mnew = fmaxf(m_r[j], mx);
      float corr = exp2f(m_r[j] - mnew);
      m_r[j] = mnew;
      float rs = 0.f;
#pragma unroll
      for (int g = 0; g < 4; ++g) {
        float p = exp2f(sv[j][g] - mnew);
        sv[j][g] = p;
        rs += p;
      }
      rs += __shfl_xor(rs, 1);
      rs += __shfl_xor(rs, 2);
      rs += __shfl_xor(rs, 4);
      rs += __shfl_xor(rs, 8);
      l_r[j] = l_r[j] * corr + rs;
#pragma unroll
      for (int g2 = 0; g2 < 8; ++g2) accO[g2][j] *= corr;
    }
    // P -> per-wave LDS (re-fragment for A-operand); wave-internal dep only
#pragma unroll
    for (int j = 0; j < 4; ++j)
#pragma unroll
      for (int g = 0; g < 4; ++g)
        sP[w][((lane >> 4) << 2) + j][g * 16 + (lane & 15)] = (_Float16)sv[j][g];
    // PV : O[16 q][128 dv] += P[16][64] * V[64][128], V streamed from global
#pragma unroll
    for (int ks = 0; ks < 2; ++ks) {
      half8 ap = *(const half8*)&sP[w][lane & 15][ks * 32 + ((lane >> 4) << 3)];
#pragma unroll
      for (int g2 = 0; g2 < 8; ++g2) {
        half8 bv = *(const half8*)(Vl + (size_t)(g2 * 16) * 1024 + kv0 + ks * 32);
        accO[g2] = __builtin_amdgcn_mfma_f32_16x16x32_f16(ap, bv, accO[g2], 0, 0, 0);
      }
    }
  }
  float inv[4];
#pragma unroll
  for (int j = 0; j < 4; ++j) inv[j] = 1.f / l_r[j];
#pragma unroll
  for (int j = 0; j < 4; ++j) {
    size_t rb = ((size_t)b * 1024 + qrb + j) * 4096 + (size_t)h * 128 + (lane & 15);
#pragma unroll
    for (int g2 = 0; g2 < 8; ++g2)
      outp[rb + g2 * 16] = (_Float16)(accO[g2][j] * inv[j]);
  }
}

// ---------------- launch ----------------
extern "C" void kernel_launch(void* const* d_in, const int* in_sizes, int n_in,
                              void* d_out, int out_size, void* d_ws, size_t ws_size,
                              hipStream_t stream) {
  const float* hs  = (const float*)d_in[0];
  const float* wq  = (const float*)d_in[1];
  const float* wkv = (const float*)d_in[2];
  const float* wo  = (const float*)d_in[3];
  char* ws = (char*)d_ws;

  const size_t OFF_HS    = 0;           // 32 MiB (later aliased by woT)
  const size_t OFF_WQKVT = 33554432;    // 96 MiB (later aliased by attn out)
  const size_t OFF_Q     = 134217728;   // 96 MiB (Q | K | Vt)
  const size_t OFF_ATTN  = OFF_WQKVT;
  const size_t OFF_WOT   = OFF_HS;

  _Float16* hs16   = (_Float16*)(ws + OFF_HS);
  _Float16* wqkvT  = (_Float16*)(ws + OFF_WQKVT);
  _Float16* qkv    = (_Float16*)(ws + OFF_Q);
  _Float16* attn   = (_Float16*)(ws + OFF_ATTN);
  _Float16* woT    = (_Float16*)(ws + OFF_WOT);

  hipFuncSetAttribute((const void*)k_gemm256,
                      hipFuncAttributeMaxDynamicSharedMemorySize, 131072);

  // 1) hs -> f16
  k_convert<<<8192, 256, 0, stream>>>(hs, hs16);
  // 2) weights -> B^T f16 (rope columns dropped)
  k_tc_qkv<<<dim3(64, 192), 256, 0, stream>>>(wq, wkv, wqkvT);
  // 3) QKV projection GEMM (256^2 8-phase), epilogue scatters Q/K/V^T
  k_gemm256<<<768, 512, 131072, stream>>>(hs16, wqkvT, (void*)qkv,
                                          4096, 12288, 4096, 1, 48, 768);
  // 4) wo -> B^T f16 (hs16 slot is dead now)
  k_tc_wo<<<dim3(64, 64), 256, 0, stream>>>(wo, woT);
  // 5) causal flash attention -> attn [t][4096] f16 (wqkvT slot is dead now)
  k_attn<<<2048, 256, 0, stream>>>(qkv, qkv + 16777216, qkv + 33554432, attn);
  // 6) output projection (256^2 8-phase) -> fp32 d_out
  k_gemm256<<<256, 512, 131072, stream>>>(attn, woT, d_out,
                                          4096, 4096, 4096, 2, 16, 256);
}

// Round 7
// 1008.469 us; speedup vs baseline: 1.3544x; 1.3544x over previous
//
#include <hip/hip_runtime.h>

// GLM MLA fused pipeline, round 7 (r6 resubmit — GPU never acquired; staging audit clean).
// r5 post-mortem: streaming attn latency-bound (MfmaUtil 2.9%). r6/r7: staged
// attention with GEMM-proven machinery: global_load_lds double-buffer,
// prefetch tile kt+1 during kt, 1 barrier + 1 vmcnt(0) per tile, T2 XOR
// swizzle (slot ^= row&7) both-sides. Per-wave softmax/PV math = r3/r4
// validated. GEMMs (256^2 8-phase, 961 TF) and converts unchanged.

typedef __attribute__((ext_vector_type(4))) float f32x4;
typedef _Float16 half8 __attribute__((ext_vector_type(8)));
typedef _Float16 half4 __attribute__((ext_vector_type(4)));

#define AS3(p) ((__attribute__((address_space(3))) void*)(p))
#define AS1(p) ((__attribute__((address_space(1))) void*)(void*)(p))

// ---------------- hs f32 -> f16 ----------------
__global__ __launch_bounds__(256) void k_convert(const float* __restrict__ src,
                                                 _Float16* __restrict__ dst) {
  int i = (blockIdx.x * 256 + threadIdx.x) * 8;
  float4 a = *(const float4*)(src + i);
  float4 b = *(const float4*)(src + i + 4);
  half8 v = { (_Float16)a.x, (_Float16)a.y, (_Float16)a.z, (_Float16)a.w,
              (_Float16)b.x, (_Float16)b.y, (_Float16)b.z, (_Float16)b.w };
  *(half8*)(dst + i) = v;
}

// ------- transpose-convert wq(nope cols)+wkv -> wqkvT [12288][4096] f16 -------
__global__ __launch_bounds__(256) void k_tc_qkv(const float* __restrict__ wq,
                                                const float* __restrict__ wkv,
                                                _Float16* __restrict__ out) {
  __shared__ __align__(16) _Float16 t[64][72];
  int k0 = blockIdx.x * 64;
  int c0 = blockIdx.y * 64;
  int tid = threadIdx.x;
  int rl = tid >> 4;
  int cl4 = (tid & 15) << 2;
  int c = c0 + cl4;
#pragma unroll
  for (int i = 0; i < 4; ++i) {
    int r = k0 + rl + i * 16;
    const float* sp;
    if (c0 < 4096) sp = wq + (size_t)r * 6144 + ((c >> 7) * 192 + (c & 127));
    else           sp = wkv + (size_t)r * 8256 + (c - 4096);
    float4 v = *(const float4*)sp;
    t[cl4 + 0][rl + i * 16] = (_Float16)v.x;
    t[cl4 + 1][rl + i * 16] = (_Float16)v.y;
    t[cl4 + 2][rl + i * 16] = (_Float16)v.z;
    t[cl4 + 3][rl + i * 16] = (_Float16)v.w;
  }
  __syncthreads();
  int r4 = (tid & 15) << 2;
#pragma unroll
  for (int i = 0; i < 4; ++i) {
    int cl = (tid >> 4) + i * 16;
    half4 p = { t[cl][r4], t[cl][r4 + 1], t[cl][r4 + 2], t[cl][r4 + 3] };
    *(half4*)(out + (size_t)(c0 + cl) * 4096 + k0 + r4) = p;
  }
}

// ------- transpose-convert wo -> woT [4096][4096] f16 -------
__global__ __launch_bounds__(256) void k_tc_wo(const float* __restrict__ wo,
                                               _Float16* __restrict__ out) {
  __shared__ __align__(16) _Float16 t[64][72];
  int k0 = blockIdx.x * 64;
  int c0 = blockIdx.y * 64;
  int tid = threadIdx.x;
  int rl = tid >> 4;
  int cl4 = (tid & 15) << 2;
#pragma unroll
  for (int i = 0; i < 4; ++i) {
    int r = k0 + rl + i * 16;
    float4 v = *(const float4*)(wo + (size_t)r * 4096 + c0 + cl4);
    t[cl4 + 0][rl + i * 16] = (_Float16)v.x;
    t[cl4 + 1][rl + i * 16] = (_Float16)v.y;
    t[cl4 + 2][rl + i * 16] = (_Float16)v.z;
    t[cl4 + 3][rl + i * 16] = (_Float16)v.w;
  }
  __syncthreads();
  int r4 = (tid & 15) << 2;
#pragma unroll
  for (int i = 0; i < 4; ++i) {
    int cl = (tid >> 4) + i * 16;
    half4 p = { t[cl][r4], t[cl][r4 + 1], t[cl][r4 + 2], t[cl][r4 + 3] };
    *(half4*)(out + (size_t)(c0 + cl) * 4096 + k0 + r4) = p;
  }
}

// ============ 256^2 8-phase GEMM (unchanged from r4, validated 961 TF) ============
#define A_OFF(d, h) ((d) * 32768 + (h) * 16384)
#define B_OFF(d, h) (65536 + (d) * 32768 + (h) * 16384)

#define STAGE(gbase, ldsoff, ktb)                                              \
  do {                                                                         \
    _Pragma("unroll") for (int i_ = 0; i_ < 2; ++i_) {                         \
      int c_ = w * 2 + i_;                                                     \
      int row_ = c_ * 16 + (lane >> 2);                                        \
      int ss_ = (lane & 3) ^ ((lane >> 3) & 3);                                \
      __builtin_amdgcn_global_load_lds(                                        \
          AS1((gbase) + (size_t)row_ * ldb + (ktb) + ss_ * 16),                \
          AS3(lds + (ldsoff) + c_ * 1024), 16, 0, 0);                          \
    }                                                                          \
  } while (0)

#define LDA(dst, d, ks, fm)                                                    \
  do {                                                                         \
    int r_ = wr * 128 + (fm) * 16 + (lane & 15);                               \
    int sl_ = (lane >> 4) ^ ((r_ >> 1) & 3);                                   \
    dst = *(const half8*)(lds + (d) * 32768 + (ks) * 16384 + r_ * 64 +         \
                          sl_ * 16);                                           \
  } while (0)

#define LDB(dst, d, ks, fn)                                                    \
  do {                                                                         \
    int r_ = wc * 64 + (fn) * 16 + (lane & 15);                                \
    int sl_ = (lane >> 4) ^ ((r_ >> 1) & 3);                                   \
    dst = *(const half8*)(lds + 65536 + (d) * 32768 + (ks) * 16384 +           \
                          r_ * 64 + sl_ * 16);                                 \
  } while (0)

#define BARRIER()                                                              \
  do {                                                                         \
    asm volatile("" ::: "memory");                                             \
    __builtin_amdgcn_s_barrier();                                              \
    asm volatile("" ::: "memory");                                             \
  } while (0)

#define MFMA16(mh)                                                             \
  do {                                                                         \
    __builtin_amdgcn_s_setprio(1);                                             \
    _Pragma("unroll") for (int mi_ = 0; mi_ < 4; ++mi_)                        \
        _Pragma("unroll") for (int ni_ = 0; ni_ < 4; ++ni_)                    \
            acc[(mh) * 4 + mi_][ni_] = __builtin_amdgcn_mfma_f32_16x16x32_f16( \
                af[mi_], bfr[ni_], acc[(mh) * 4 + mi_][ni_], 0, 0, 0);         \
    __builtin_amdgcn_s_setprio(0);                                             \
  } while (0)

__global__ __launch_bounds__(512, 2) void k_gemm256(
    const _Float16* __restrict__ A, const _Float16* __restrict__ Bt,
    void* __restrict__ outp, int M, int N, int K, int mode, int ntn, int nblk) {
  extern __shared__ __align__(16) char lds[];
  int tid = threadIdx.x, lane = tid & 63, w = tid >> 6;
  int wr = w >> 2, wc = w & 3;
  int bid = blockIdx.x;
  int sid = (bid & 7) * (nblk >> 3) + (bid >> 3);
  int mt = sid / ntn, nt = sid % ntn;
  int m0 = mt * 256, n0 = nt * 256;

  const char* Ab = (const char*)(A + (size_t)m0 * K);
  const char* Bb = (const char*)(Bt + (size_t)n0 * K);
  size_t ldb = (size_t)K * 2;

  f32x4 acc[8][4];
#pragma unroll
  for (int i = 0; i < 8; ++i)
#pragma unroll
    for (int j = 0; j < 4; ++j) acc[i][j] = (f32x4){0.f, 0.f, 0.f, 0.f};
  half8 af[4], bfr[4];

  int NT = K >> 6;
  STAGE(Ab, A_OFF(0, 0), 0);
  STAGE(Bb, B_OFF(0, 0), 0);
  STAGE(Ab, A_OFF(0, 1), 64);
  STAGE(Bb, B_OFF(0, 1), 64);
  STAGE(Ab, A_OFF(1, 0), 128);
  STAGE(Bb, B_OFF(1, 0), 128);
  asm volatile("s_waitcnt vmcnt(4)" ::: "memory");
  BARRIER();

  for (int k = 0; k < NT; ++k) {
    int d = k & 1, dn = d ^ 1;
    int ktb1 = (k + 1) << 7, ktb2 = (k + 2) << 7;
    bool s1 = (k + 1 < NT), s2 = (k + 2 < NT);
    LDB(bfr[0], d, 0, 0); LDB(bfr[1], d, 0, 1);
    LDB(bfr[2], d, 0, 2); LDB(bfr[3], d, 0, 3);
    LDA(af[0], d, 0, 0); LDA(af[1], d, 0, 1);
    LDA(af[2], d, 0, 2); LDA(af[3], d, 0, 3);
    if (s1) STAGE(Ab, A_OFF(dn, 1), ktb1 + 64);
    BARRIER();
    MFMA16(0);
    BARRIER();
    LDA(af[0], d, 0, 4); LDA(af[1], d, 0, 5);
    LDA(af[2], d, 0, 6); LDA(af[3], d, 0, 7);
    if (s1) STAGE(Bb, B_OFF(dn, 1), ktb1 + 64);
    BARRIER();
    MFMA16(1);
    BARRIER();
    LDB(bfr[0], d, 1, 0); LDB(bfr[1], d, 1, 1);
    LDB(bfr[2], d, 1, 2); LDB(bfr[3], d, 1, 3);
    LDA(af[0], d, 1, 0); LDA(af[1], d, 1, 1);
    LDA(af[2], d, 1, 2); LDA(af[3], d, 1, 3);
    if (s2) STAGE(Ab, A_OFF(d, 0), ktb2);
    BARRIER();
    MFMA16(0);
    BARRIER();
    LDA(af[0], d, 1, 4); LDA(af[1], d, 1, 5);
    LDA(af[2], d, 1, 6); LDA(af[3], d, 1, 7);
    if (s2) {
      STAGE(Bb, B_OFF(d, 0), ktb2);
      asm volatile("s_waitcnt vmcnt(4)" ::: "memory");
    } else {
      asm volatile("s_waitcnt vmcnt(0)" ::: "memory");
    }
    BARRIER();
    MFMA16(1);
    BARRIER();
  }

  if (mode == 2) {
    float* O = (float*)outp;
#pragma unroll
    for (int fm = 0; fm < 8; ++fm)
#pragma unroll
      for (int j = 0; j < 4; ++j) {
        int r = m0 + wr * 128 + fm * 16 + ((lane >> 4) << 2) + j;
        float* op = O + (size_t)r * N + n0 + wc * 64 + (lane & 15);
#pragma unroll
        for (int ni = 0; ni < 4; ++ni) op[ni * 16] = acc[fm][ni][j];
      }
  } else {
    _Float16* Q = (_Float16*)outp;
    _Float16* Kk = Q + 16777216;
    _Float16* Vt = Q + 33554432;
    int cb0 = n0 + wc * 64;
    int seg = cb0 >> 12;
    int h = (cb0 >> 7) & 31;
    int dbase = cb0 & 127;
    if (seg < 2) {
      _Float16* Obuf = (seg == 0) ? Q : Kk;
#pragma unroll
      for (int fm = 0; fm < 8; ++fm) {
        int t0 = m0 + wr * 128 + fm * 16 + ((lane >> 4) << 2);
        int bb = t0 >> 10, s0 = t0 & 1023;
        size_t base = ((size_t)bb * 32 + h) * 1024;
#pragma unroll
        for (int j = 0; j < 4; ++j)
#pragma unroll
          for (int ni = 0; ni < 4; ++ni)
            Obuf[(base + s0 + j) * 128 + dbase + ni * 16 + (lane & 15)] =
                (_Float16)acc[fm][ni][j];
      }
    } else {
#pragma unroll
      for (int fm = 0; fm < 8; ++fm) {
        int t0 = m0 + wr * 128 + fm * 16 + ((lane >> 4) << 2);
        int bb = t0 >> 10, s0 = t0 & 1023;
#pragma unroll
        for (int ni = 0; ni < 4; ++ni) {
          int dd = dbase + ni * 16 + (lane & 15);
          half4 p = { (_Float16)acc[fm][ni][0], (_Float16)acc[fm][ni][1],
                      (_Float16)acc[fm][ni][2], (_Float16)acc[fm][ni][3] };
          *(half4*)(Vt + (((size_t)bb * 32 + h) * 128 + dd) * 1024 + s0) = p;
        }
      }
    }
  }
}

// ---------------- causal flash attention, staged+dbuf+swizzle ----------------
// Q,K: [B,H,S,128] f16 ; Vt: [B,H,128,S] f16 ; out: [B*S][H*128] f16
// LDS (dynamic, 74752 B): K[2][64][128] swz | V[2][128][64] swz | sP[4][16][72]
// swizzle: 16B slot ^= (row & 7), both-sides (pre-swizzled global source).
#define KOFF(d) ((d) * 16384)
#define VOFF(d) (32768 + (d) * 16384)
#define POFF 65536

#define ASTAGE_K(d, kv0)                                                       \
  do {                                                                         \
    _Pragma("unroll") for (int j_ = 0; j_ < 4; ++j_) {                         \
      int r_ = j_ * 16 + w * 4 + (lane >> 4);                                  \
      int sg_ = (lane & 15) ^ (r_ & 7);                                        \
      __builtin_amdgcn_global_load_lds(                                        \
          AS1(Kp + (size_t)((kv0) + r_) * 128 + sg_ * 8),                      \
          AS3(alds + KOFF(d) + j_ * 4096 + w * 1024), 16, 0, 0);               \
    }                                                                          \
  } while (0)

#define ASTAGE_V(d, kv0)                                                       \
  do {                                                                         \
    _Pragma("unroll") for (int j_ = 0; j_ < 4; ++j_) {                         \
      int r_ = j_ * 32 + w * 8 + (lane >> 3);                                  \
      int sg_ = (lane & 7) ^ (r_ & 7);                                         \
      __builtin_amdgcn_global_load_lds(                                        \
          AS1(Vp + (size_t)r_ * 1024 + (kv0) + sg_ * 8),                       \
          AS3(alds + VOFF(d) + j_ * 4096 + w * 1024), 16, 0, 0);               \
    }                                                                          \
  } while (0)

#define LDK(dst, d, g, ks)                                                     \
  do {                                                                         \
    int rr_ = (g) * 16 + (lane & 15);                                          \
    int sl_ = ((ks) * 4 + (lane >> 4)) ^ (rr_ & 7);                            \
    dst = *(const half8*)(alds + KOFF(d) + rr_ * 256 + sl_ * 16);              \
  } while (0)

#define LDV(dst, d, g2, ks)                                                    \
  do {                                                                         \
    int rr_ = (g2) * 16 + (lane & 15);                                         \
    int sl_ = ((ks) * 4 + (lane >> 4)) ^ (rr_ & 7);                            \
    dst = *(const half8*)(alds + VOFF(d) + rr_ * 128 + sl_ * 16);              \
  } while (0)

__global__ __launch_bounds__(256) void k_attn(const _Float16* __restrict__ Qb,
                                              const _Float16* __restrict__ Kb,
                                              const _Float16* __restrict__ Vtb,
                                              _Float16* __restrict__ outp) {
  extern __shared__ __align__(16) char alds[];
  const float SCL = 0.10411834905624762f;  // 192^-0.5 * log2(e)
  int tid = threadIdx.x;
  int lane = tid & 63;
  int w = tid >> 6;
  int bid = blockIdx.x;
  int qt = 15 - (bid >> 7);   // longest-first
  int bh = bid & 127;
  int q0 = qt * 64;
  int b = bh >> 5, h = bh & 31;
  const _Float16* Qp = Qb + (size_t)bh * (1024 * 128);
  const _Float16* Kp = Kb + (size_t)bh * (1024 * 128);
  const _Float16* Vp = Vtb + (size_t)bh * (128 * 1024);
  _Float16* sPw = (_Float16*)(alds + POFF) + w * (16 * 72);

  half8 aQ[4];
  {
    const _Float16* qr = Qp + (size_t)(q0 + w * 16 + (lane & 15)) * 128 + ((lane >> 4) << 3);
#pragma unroll
    for (int ks = 0; ks < 4; ++ks) aQ[ks] = *(const half8*)(qr + ks * 32);
  }
  f32x4 accO[8];
#pragma unroll
  for (int g = 0; g < 8; ++g) accO[g] = (f32x4){0.f, 0.f, 0.f, 0.f};
  float m_r[4] = { -__builtin_inff(), -__builtin_inff(), -__builtin_inff(), -__builtin_inff() };
  float l_r[4] = { 0.f, 0.f, 0.f, 0.f };

  int ntile = qt + 1;
  int qrb = q0 + w * 16 + ((lane >> 4) << 2);

  // prologue: stage tile 0
  ASTAGE_K(0, 0);
  ASTAGE_V(0, 0);
  asm volatile("s_waitcnt vmcnt(0)" ::: "memory");
  BARRIER();

  for (int kt = 0; kt < ntile; ++kt) {
    int kv0 = kt * 64;
    int d = kt & 1;
    bool more = (kt + 1 < ntile);
    if (more) {
      ASTAGE_K(d ^ 1, kv0 + 64);
      ASTAGE_V(d ^ 1, kv0 + 64);
    }
    // QK^T : 16 q-rows x 64 kv from swizzled LDS
    f32x4 sc[4];
#pragma unroll
    for (int g = 0; g < 4; ++g) {
      f32x4 c = (f32x4){0.f, 0.f, 0.f, 0.f};
#pragma unroll
      for (int ks = 0; ks < 4; ++ks) {
        half8 bk;
        LDK(bk, d, g, ks);
        c = __builtin_amdgcn_mfma_f32_16x16x32_f16(aQ[ks], bk, c, 0, 0, 0);
      }
      sc[g] = c;
    }
    // mask + online softmax (log2 domain)
    bool diag = (kt == ntile - 1);
    float sv[4][4];  // [j][g]
#pragma unroll
    for (int g = 0; g < 4; ++g) {
      int kvc = kv0 + g * 16 + (lane & 15);
#pragma unroll
      for (int j = 0; j < 4; ++j) {
        float s = sc[g][j] * SCL;
        if (diag && kvc > qrb + j) s = -__builtin_inff();
        sv[j][g] = s;
      }
    }
#pragma unroll
    for (int j = 0; j < 4; ++j) {
      float mx = fmaxf(fmaxf(sv[j][0], sv[j][1]), fmaxf(sv[j][2], sv[j][3]));
      mx = fmaxf(mx, __shfl_xor(mx, 1));
      mx = fmaxf(mx, __shfl_xor(mx, 2));
      mx = fmaxf(mx, __shfl_xor(mx, 4));
      mx = fmaxf(mx, __shfl_xor(mx, 8));
      float mnew = fmaxf(m_r[j], mx);
      float corr = exp2f(m_r[j] - mnew);
      m_r[j] = mnew;
      float rs = 0.f;
#pragma unroll
      for (int g = 0; g < 4; ++g) {
        float p = exp2f(sv[j][g] - mnew);
        sv[j][g] = p;
        rs += p;
      }
      rs += __shfl_xor(rs, 1);
      rs += __shfl_xor(rs, 2);
      rs += __shfl_xor(rs, 4);
      rs += __shfl_xor(rs, 8);
      l_r[j] = l_r[j] * corr + rs;
#pragma unroll
      for (int g2 = 0; g2 < 8; ++g2) accO[g2][j] *= corr;
    }
    // P -> per-wave LDS (wave-internal ordering only)
#pragma unroll
    for (int j = 0; j < 4; ++j)
#pragma unroll
      for (int g = 0; g < 4; ++g)
        sPw[(((lane >> 4) << 2) + j) * 72 + g * 16 + (lane & 15)] = (_Float16)sv[j][g];
    // PV : O[16 q][128 dv] += P[16][64] * V[64][128]
#pragma unroll
    for (int ks = 0; ks < 2; ++ks) {
      half8 ap = *(const half8*)(sPw + (lane & 15) * 72 + ks * 32 + ((lane >> 4) << 3));
#pragma unroll
      for (int g2 = 0; g2 < 8; ++g2) {
        half8 bv;
        LDV(bv, d, g2, ks);
        accO[g2] = __builtin_amdgcn_mfma_f32_16x16x32_f16(ap, bv, accO[g2], 0, 0, 0);
      }
    }
    // tile boundary: staged tile kt+1 must be complete; all waves done with buf d
    if (more) asm volatile("s_waitcnt vmcnt(0)" ::: "memory");
    BARRIER();
  }
  float inv[4];
#pragma unroll
  for (int j = 0; j < 4; ++j) inv[j] = 1.f / l_r[j];
#pragma unroll
  for (int j = 0; j < 4; ++j) {
    size_t rb = ((size_t)b * 1024 + qrb + j) * 4096 + (size_t)h * 128 + (lane & 15);
#pragma unroll
    for (int g2 = 0; g2 < 8; ++g2)
      outp[rb + g2 * 16] = (_Float16)(accO[g2][j] * inv[j]);
  }
}

// ---------------- launch ----------------
extern "C" void kernel_launch(void* const* d_in, const int* in_sizes, int n_in,
                              void* d_out, int out_size, void* d_ws, size_t ws_size,
                              hipStream_t stream) {
  const float* hs  = (const float*)d_in[0];
  const float* wq  = (const float*)d_in[1];
  const float* wkv = (const float*)d_in[2];
  const float* wo  = (const float*)d_in[3];
  char* ws = (char*)d_ws;

  const size_t OFF_HS    = 0;           // 32 MiB (later aliased by woT)
  const size_t OFF_WQKVT = 33554432;    // 96 MiB (later aliased by attn out)
  const size_t OFF_Q     = 134217728;   // 96 MiB (Q | K | Vt)
  const size_t OFF_ATTN  = OFF_WQKVT;
  const size_t OFF_WOT   = OFF_HS;

  _Float16* hs16   = (_Float16*)(ws + OFF_HS);
  _Float16* wqkvT  = (_Float16*)(ws + OFF_WQKVT);
  _Float16* qkv    = (_Float16*)(ws + OFF_Q);
  _Float16* attn   = (_Float16*)(ws + OFF_ATTN);
  _Float16* woT    = (_Float16*)(ws + OFF_WOT);

  hipFuncSetAttribute((const void*)k_gemm256,
                      hipFuncAttributeMaxDynamicSharedMemorySize, 131072);
  hipFuncSetAttribute((const void*)k_attn,
                      hipFuncAttributeMaxDynamicSharedMemorySize, 74752);

  // 1) hs -> f16
  k_convert<<<8192, 256, 0, stream>>>(hs, hs16);
  // 2) weights -> B^T f16 (rope columns dropped)
  k_tc_qkv<<<dim3(64, 192), 256, 0, stream>>>(wq, wkv, wqkvT);
  // 3) QKV projection GEMM (256^2 8-phase), epilogue scatters Q/K/V^T
  k_gemm256<<<768, 512, 131072, stream>>>(hs16, wqkvT, (void*)qkv,
                                          4096, 12288, 4096, 1, 48, 768);
  // 4) wo -> B^T f16 (hs16 slot is dead now)
  k_tc_wo<<<dim3(64, 64), 256, 0, stream>>>(wo, woT);
  // 5) causal flash attention -> attn [t][4096] f16 (wqkvT slot is dead now)
  k_attn<<<2048, 256, 74752, stream>>>(qkv, qkv + 16777216, qkv + 33554432, attn);
  // 6) output projection (256^2 8-phase) -> fp32 d_out
  k_gemm256<<<256, 512, 131072, stream>>>(attn, woT, d_out,
                                          4096, 4096, 4096, 2, 16, 256);
}

// Round 8
// 997.478 us; speedup vs baseline: 1.3694x; 1.0110x over previous
//
#include <hip/hip_runtime.h>

// GLM MLA fused pipeline, round 8.
// r7 post-mortem: attn fixed (~137us, as predicted). Residual 451us for
// GEMM2+prep is opaque (shared kernel names). r8: (1) template-ize GEMM ->
// distinct names for profiling; (2) rewrite transpose-converts with 128x64
// tiles + half8 16B stores (suspected ~300us prep sink vs 76us ideal).
// GEMM inner loop + attention byte-identical to r7.

typedef __attribute__((ext_vector_type(4))) float f32x4;
typedef _Float16 half8 __attribute__((ext_vector_type(8)));
typedef _Float16 half4 __attribute__((ext_vector_type(4)));

#define AS3(p) ((__attribute__((address_space(3))) void*)(p))
#define AS1(p) ((__attribute__((address_space(1))) void*)(void*)(p))

// ---------------- hs f32 -> f16 ----------------
__global__ __launch_bounds__(256) void k_convert(const float* __restrict__ src,
                                                 _Float16* __restrict__ dst) {
  int i = (blockIdx.x * 256 + threadIdx.x) * 8;
  float4 a = *(const float4*)(src + i);
  float4 b = *(const float4*)(src + i + 4);
  half8 v = { (_Float16)a.x, (_Float16)a.y, (_Float16)a.z, (_Float16)a.w,
              (_Float16)b.x, (_Float16)b.y, (_Float16)b.z, (_Float16)b.w };
  *(half8*)(dst + i) = v;
}

// ------- transpose-convert, 128k x 64c tile, half8 stores -------
// SRC 0: wo [4096][4096], out woT[4096][4096]
// SRC 1: wq/wkv -> wqkvT [12288][4096] (rope cols dropped)
template <int SRC>
__global__ __launch_bounds__(256) void k_tc(const float* __restrict__ s0,
                                            const float* __restrict__ s1,
                                            _Float16* __restrict__ out) {
  __shared__ __align__(16) _Float16 t[64][136];
  int k0 = blockIdx.x * 128;
  int c0 = blockIdx.y * 64;
  int tid = threadIdx.x;
  int rl = tid >> 4;          // 0..15
  int cl4 = (tid & 15) << 2;  // 0..60
  int c = c0 + cl4;
  const float* sp;
  size_t ld;
  if (SRC == 0)          { sp = s0 + c;                                ld = 4096; }
  else if (c0 < 4096)    { sp = s0 + ((c >> 7) * 192 + (c & 127));     ld = 6144; }
  else                   { sp = s1 + (c - 4096);                       ld = 8256; }
#pragma unroll
  for (int i = 0; i < 8; ++i) {
    int r = rl + i * 16;  // 0..127
    float4 v = *(const float4*)(sp + (size_t)(k0 + r) * ld);
    t[cl4 + 0][r] = (_Float16)v.x;
    t[cl4 + 1][r] = (_Float16)v.y;
    t[cl4 + 2][r] = (_Float16)v.z;
    t[cl4 + 3][r] = (_Float16)v.w;
  }
  __syncthreads();
  int k8 = (tid & 15) << 3;  // 0..120
#pragma unroll
  for (int j = 0; j < 4; ++j) {
    int cl = (tid >> 4) + j * 16;  // 0..63
    half8 p = *(const half8*)&t[cl][k8];
    *(half8*)(out + (size_t)(c0 + cl) * 4096 + k0 + k8) = p;
  }
}

// ============ 256^2 8-phase GEMM (inner loop identical to r7; MODE templated
// for distinct profile names; mode branch now compile-time) ============
#define A_OFF(d, h) ((d) * 32768 + (h) * 16384)
#define B_OFF(d, h) (65536 + (d) * 32768 + (h) * 16384)

#define STAGE(gbase, ldsoff, ktb)                                              \
  do {                                                                         \
    _Pragma("unroll") for (int i_ = 0; i_ < 2; ++i_) {                         \
      int c_ = w * 2 + i_;                                                     \
      int row_ = c_ * 16 + (lane >> 2);                                        \
      int ss_ = (lane & 3) ^ ((lane >> 3) & 3);                                \
      __builtin_amdgcn_global_load_lds(                                        \
          AS1((gbase) + (size_t)row_ * ldb + (ktb) + ss_ * 16),                \
          AS3(lds + (ldsoff) + c_ * 1024), 16, 0, 0);                          \
    }                                                                          \
  } while (0)

#define LDA(dst, d, ks, fm)                                                    \
  do {                                                                         \
    int r_ = wr * 128 + (fm) * 16 + (lane & 15);                               \
    int sl_ = (lane >> 4) ^ ((r_ >> 1) & 3);                                   \
    dst = *(const half8*)(lds + (d) * 32768 + (ks) * 16384 + r_ * 64 +         \
                          sl_ * 16);                                           \
  } while (0)

#define LDB(dst, d, ks, fn)                                                    \
  do {                                                                         \
    int r_ = wc * 64 + (fn) * 16 + (lane & 15);                                \
    int sl_ = (lane >> 4) ^ ((r_ >> 1) & 3);                                   \
    dst = *(const half8*)(lds + 65536 + (d) * 32768 + (ks) * 16384 +           \
                          r_ * 64 + sl_ * 16);                                 \
  } while (0)

#define BARRIER()                                                              \
  do {                                                                         \
    asm volatile("" ::: "memory");                                             \
    __builtin_amdgcn_s_barrier();                                              \
    asm volatile("" ::: "memory");                                             \
  } while (0)

#define MFMA16(mh)                                                             \
  do {                                                                         \
    __builtin_amdgcn_s_setprio(1);                                             \
    _Pragma("unroll") for (int mi_ = 0; mi_ < 4; ++mi_)                        \
        _Pragma("unroll") for (int ni_ = 0; ni_ < 4; ++ni_)                    \
            acc[(mh) * 4 + mi_][ni_] = __builtin_amdgcn_mfma_f32_16x16x32_f16( \
                af[mi_], bfr[ni_], acc[(mh) * 4 + mi_][ni_], 0, 0, 0);         \
    __builtin_amdgcn_s_setprio(0);                                             \
  } while (0)

template <int MODE>
__global__ __launch_bounds__(512, 2) void k_gemm256(
    const _Float16* __restrict__ A, const _Float16* __restrict__ Bt,
    void* __restrict__ outp, int M, int N, int K, int ntn, int nblk) {
  extern __shared__ __align__(16) char lds[];
  int tid = threadIdx.x, lane = tid & 63, w = tid >> 6;
  int wr = w >> 2, wc = w & 3;
  int bid = blockIdx.x;
  int sid = (bid & 7) * (nblk >> 3) + (bid >> 3);
  int mt = sid / ntn, nt = sid % ntn;
  int m0 = mt * 256, n0 = nt * 256;

  const char* Ab = (const char*)(A + (size_t)m0 * K);
  const char* Bb = (const char*)(Bt + (size_t)n0 * K);
  size_t ldb = (size_t)K * 2;

  f32x4 acc[8][4];
#pragma unroll
  for (int i = 0; i < 8; ++i)
#pragma unroll
    for (int j = 0; j < 4; ++j) acc[i][j] = (f32x4){0.f, 0.f, 0.f, 0.f};
  half8 af[4], bfr[4];

  int NT = K >> 6;
  STAGE(Ab, A_OFF(0, 0), 0);
  STAGE(Bb, B_OFF(0, 0), 0);
  STAGE(Ab, A_OFF(0, 1), 64);
  STAGE(Bb, B_OFF(0, 1), 64);
  STAGE(Ab, A_OFF(1, 0), 128);
  STAGE(Bb, B_OFF(1, 0), 128);
  asm volatile("s_waitcnt vmcnt(4)" ::: "memory");
  BARRIER();

  for (int k = 0; k < NT; ++k) {
    int d = k & 1, dn = d ^ 1;
    int ktb1 = (k + 1) << 7, ktb2 = (k + 2) << 7;
    bool s1 = (k + 1 < NT), s2 = (k + 2 < NT);
    LDB(bfr[0], d, 0, 0); LDB(bfr[1], d, 0, 1);
    LDB(bfr[2], d, 0, 2); LDB(bfr[3], d, 0, 3);
    LDA(af[0], d, 0, 0); LDA(af[1], d, 0, 1);
    LDA(af[2], d, 0, 2); LDA(af[3], d, 0, 3);
    if (s1) STAGE(Ab, A_OFF(dn, 1), ktb1 + 64);
    BARRIER();
    MFMA16(0);
    BARRIER();
    LDA(af[0], d, 0, 4); LDA(af[1], d, 0, 5);
    LDA(af[2], d, 0, 6); LDA(af[3], d, 0, 7);
    if (s1) STAGE(Bb, B_OFF(dn, 1), ktb1 + 64);
    BARRIER();
    MFMA16(1);
    BARRIER();
    LDB(bfr[0], d, 1, 0); LDB(bfr[1], d, 1, 1);
    LDB(bfr[2], d, 1, 2); LDB(bfr[3], d, 1, 3);
    LDA(af[0], d, 1, 0); LDA(af[1], d, 1, 1);
    LDA(af[2], d, 1, 2); LDA(af[3], d, 1, 3);
    if (s2) STAGE(Ab, A_OFF(d, 0), ktb2);
    BARRIER();
    MFMA16(0);
    BARRIER();
    LDA(af[0], d, 1, 4); LDA(af[1], d, 1, 5);
    LDA(af[2], d, 1, 6); LDA(af[3], d, 1, 7);
    if (s2) {
      STAGE(Bb, B_OFF(d, 0), ktb2);
      asm volatile("s_waitcnt vmcnt(4)" ::: "memory");
    } else {
      asm volatile("s_waitcnt vmcnt(0)" ::: "memory");
    }
    BARRIER();
    MFMA16(1);
    BARRIER();
  }

  if (MODE == 2) {
    float* O = (float*)outp;
#pragma unroll
    for (int fm = 0; fm < 8; ++fm)
#pragma unroll
      for (int j = 0; j < 4; ++j) {
        int r = m0 + wr * 128 + fm * 16 + ((lane >> 4) << 2) + j;
        float* op = O + (size_t)r * N + n0 + wc * 64 + (lane & 15);
#pragma unroll
        for (int ni = 0; ni < 4; ++ni) op[ni * 16] = acc[fm][ni][j];
      }
  } else {
    _Float16* Q = (_Float16*)outp;
    _Float16* Kk = Q + 16777216;
    _Float16* Vt = Q + 33554432;
    int cb0 = n0 + wc * 64;
    int seg = cb0 >> 12;
    int h = (cb0 >> 7) & 31;
    int dbase = cb0 & 127;
    if (seg < 2) {
      _Float16* Obuf = (seg == 0) ? Q : Kk;
#pragma unroll
      for (int fm = 0; fm < 8; ++fm) {
        int t0 = m0 + wr * 128 + fm * 16 + ((lane >> 4) << 2);
        int bb = t0 >> 10, s0 = t0 & 1023;
        size_t base = ((size_t)bb * 32 + h) * 1024;
#pragma unroll
        for (int j = 0; j < 4; ++j)
#pragma unroll
          for (int ni = 0; ni < 4; ++ni)
            Obuf[(base + s0 + j) * 128 + dbase + ni * 16 + (lane & 15)] =
                (_Float16)acc[fm][ni][j];
      }
    } else {
#pragma unroll
      for (int fm = 0; fm < 8; ++fm) {
        int t0 = m0 + wr * 128 + fm * 16 + ((lane >> 4) << 2);
        int bb = t0 >> 10, s0 = t0 & 1023;
#pragma unroll
        for (int ni = 0; ni < 4; ++ni) {
          int dd = dbase + ni * 16 + (lane & 15);
          half4 p = { (_Float16)acc[fm][ni][0], (_Float16)acc[fm][ni][1],
                      (_Float16)acc[fm][ni][2], (_Float16)acc[fm][ni][3] };
          *(half4*)(Vt + (((size_t)bb * 32 + h) * 128 + dd) * 1024 + s0) = p;
        }
      }
    }
  }
}

// ---------------- causal flash attention (unchanged from r7) ----------------
#define KOFF(d) ((d) * 16384)
#define VOFF(d) (32768 + (d) * 16384)
#define POFF 65536

#define ASTAGE_K(d, kv0)                                                       \
  do {                                                                         \
    _Pragma("unroll") for (int j_ = 0; j_ < 4; ++j_) {                         \
      int r_ = j_ * 16 + w * 4 + (lane >> 4);                                  \
      int sg_ = (lane & 15) ^ (r_ & 7);                                        \
      __builtin_amdgcn_global_load_lds(                                        \
          AS1(Kp + (size_t)((kv0) + r_) * 128 + sg_ * 8),                      \
          AS3(alds + KOFF(d) + j_ * 4096 + w * 1024), 16, 0, 0);               \
    }                                                                          \
  } while (0)

#define ASTAGE_V(d, kv0)                                                       \
  do {                                                                         \
    _Pragma("unroll") for (int j_ = 0; j_ < 4; ++j_) {                         \
      int r_ = j_ * 32 + w * 8 + (lane >> 3);                                  \
      int sg_ = (lane & 7) ^ (r_ & 7);                                         \
      __builtin_amdgcn_global_load_lds(                                        \
          AS1(Vp + (size_t)r_ * 1024 + (kv0) + sg_ * 8),                       \
          AS3(alds + VOFF(d) + j_ * 4096 + w * 1024), 16, 0, 0);               \
    }                                                                          \
  } while (0)

#define LDK(dst, d, g, ks)                                                     \
  do {                                                                         \
    int rr_ = (g) * 16 + (lane & 15);                                          \
    int sl_ = ((ks) * 4 + (lane >> 4)) ^ (rr_ & 7);                            \
    dst = *(const half8*)(alds + KOFF(d) + rr_ * 256 + sl_ * 16);              \
  } while (0)

#define LDV(dst, d, g2, ks)                                                    \
  do {                                                                         \
    int rr_ = (g2) * 16 + (lane & 15);                                         \
    int sl_ = ((ks) * 4 + (lane >> 4)) ^ (rr_ & 7);                            \
    dst = *(const half8*)(alds + VOFF(d) + rr_ * 128 + sl_ * 16);              \
  } while (0)

__global__ __launch_bounds__(256) void k_attn(const _Float16* __restrict__ Qb,
                                              const _Float16* __restrict__ Kb,
                                              const _Float16* __restrict__ Vtb,
                                              _Float16* __restrict__ outp) {
  extern __shared__ __align__(16) char alds[];
  const float SCL = 0.10411834905624762f;  // 192^-0.5 * log2(e)
  int tid = threadIdx.x;
  int lane = tid & 63;
  int w = tid >> 6;
  int bid = blockIdx.x;
  int qt = 15 - (bid >> 7);   // longest-first
  int bh = bid & 127;
  int q0 = qt * 64;
  int b = bh >> 5, h = bh & 31;
  const _Float16* Qp = Qb + (size_t)bh * (1024 * 128);
  const _Float16* Kp = Kb + (size_t)bh * (1024 * 128);
  const _Float16* Vp = Vtb + (size_t)bh * (128 * 1024);
  _Float16* sPw = (_Float16*)(alds + POFF) + w * (16 * 72);

  half8 aQ[4];
  {
    const _Float16* qr = Qp + (size_t)(q0 + w * 16 + (lane & 15)) * 128 + ((lane >> 4) << 3);
#pragma unroll
    for (int ks = 0; ks < 4; ++ks) aQ[ks] = *(const half8*)(qr + ks * 32);
  }
  f32x4 accO[8];
#pragma unroll
  for (int g = 0; g < 8; ++g) accO[g] = (f32x4){0.f, 0.f, 0.f, 0.f};
  float m_r[4] = { -__builtin_inff(), -__builtin_inff(), -__builtin_inff(), -__builtin_inff() };
  float l_r[4] = { 0.f, 0.f, 0.f, 0.f };

  int ntile = qt + 1;
  int qrb = q0 + w * 16 + ((lane >> 4) << 2);

  ASTAGE_K(0, 0);
  ASTAGE_V(0, 0);
  asm volatile("s_waitcnt vmcnt(0)" ::: "memory");
  BARRIER();

  for (int kt = 0; kt < ntile; ++kt) {
    int kv0 = kt * 64;
    int d = kt & 1;
    bool more = (kt + 1 < ntile);
    if (more) {
      ASTAGE_K(d ^ 1, kv0 + 64);
      ASTAGE_V(d ^ 1, kv0 + 64);
    }
    f32x4 sc[4];
#pragma unroll
    for (int g = 0; g < 4; ++g) {
      f32x4 c = (f32x4){0.f, 0.f, 0.f, 0.f};
#pragma unroll
      for (int ks = 0; ks < 4; ++ks) {
        half8 bk;
        LDK(bk, d, g, ks);
        c = __builtin_amdgcn_mfma_f32_16x16x32_f16(aQ[ks], bk, c, 0, 0, 0);
      }
      sc[g] = c;
    }
    bool diag = (kt == ntile - 1);
    float sv[4][4];
#pragma unroll
    for (int g = 0; g < 4; ++g) {
      int kvc = kv0 + g * 16 + (lane & 15);
#pragma unroll
      for (int j = 0; j < 4; ++j) {
        float s = sc[g][j] * SCL;
        if (diag && kvc > qrb + j) s = -__builtin_inff();
        sv[j][g] = s;
      }
    }
#pragma unroll
    for (int j = 0; j < 4; ++j) {
      float mx = fmaxf(fmaxf(sv[j][0], sv[j][1]), fmaxf(sv[j][2], sv[j][3]));
      mx = fmaxf(mx, __shfl_xor(mx, 1));
      mx = fmaxf(mx, __shfl_xor(mx, 2));
      mx = fmaxf(mx, __shfl_xor(mx, 4));
      mx = fmaxf(mx, __shfl_xor(mx, 8));
      float mnew = fmaxf(m_r[j], mx);
      float corr = exp2f(m_r[j] - mnew);
      m_r[j] = mnew;
      float rs = 0.f;
#pragma unroll
      for (int g = 0; g < 4; ++g) {
        float p = exp2f(sv[j][g] - mnew);
        sv[j][g] = p;
        rs += p;
      }
      rs += __shfl_xor(rs, 1);
      rs += __shfl_xor(rs, 2);
      rs += __shfl_xor(rs, 4);
      rs += __shfl_xor(rs, 8);
      l_r[j] = l_r[j] * corr + rs;
#pragma unroll
      for (int g2 = 0; g2 < 8; ++g2) accO[g2][j] *= corr;
    }
#pragma unroll
    for (int j = 0; j < 4; ++j)
#pragma unroll
      for (int g = 0; g < 4; ++g)
        sPw[(((lane >> 4) << 2) + j) * 72 + g * 16 + (lane & 15)] = (_Float16)sv[j][g];
#pragma unroll
    for (int ks = 0; ks < 2; ++ks) {
      half8 ap = *(const half8*)(sPw + (lane & 15) * 72 + ks * 32 + ((lane >> 4) << 3));
#pragma unroll
      for (int g2 = 0; g2 < 8; ++g2) {
        half8 bv;
        LDV(bv, d, g2, ks);
        accO[g2] = __builtin_amdgcn_mfma_f32_16x16x32_f16(ap, bv, accO[g2], 0, 0, 0);
      }
    }
    if (more) asm volatile("s_waitcnt vmcnt(0)" ::: "memory");
    BARRIER();
  }
  float inv[4];
#pragma unroll
  for (int j = 0; j < 4; ++j) inv[j] = 1.f / l_r[j];
#pragma unroll
  for (int j = 0; j < 4; ++j) {
    size_t rb = ((size_t)b * 1024 + qrb + j) * 4096 + (size_t)h * 128 + (lane & 15);
#pragma unroll
    for (int g2 = 0; g2 < 8; ++g2)
      outp[rb + g2 * 16] = (_Float16)(accO[g2][j] * inv[j]);
  }
}

// ---------------- launch ----------------
extern "C" void kernel_launch(void* const* d_in, const int* in_sizes, int n_in,
                              void* d_out, int out_size, void* d_ws, size_t ws_size,
                              hipStream_t stream) {
  const float* hs  = (const float*)d_in[0];
  const float* wq  = (const float*)d_in[1];
  const float* wkv = (const float*)d_in[2];
  const float* wo  = (const float*)d_in[3];
  char* ws = (char*)d_ws;

  const size_t OFF_HS    = 0;           // 32 MiB (later aliased by woT)
  const size_t OFF_WQKVT = 33554432;    // 96 MiB (later aliased by attn out)
  const size_t OFF_Q     = 134217728;   // 96 MiB (Q | K | Vt)
  const size_t OFF_ATTN  = OFF_WQKVT;
  const size_t OFF_WOT   = OFF_HS;

  _Float16* hs16   = (_Float16*)(ws + OFF_HS);
  _Float16* wqkvT  = (_Float16*)(ws + OFF_WQKVT);
  _Float16* qkv    = (_Float16*)(ws + OFF_Q);
  _Float16* attn   = (_Float16*)(ws + OFF_ATTN);
  _Float16* woT    = (_Float16*)(ws + OFF_WOT);

  hipFuncSetAttribute((const void*)k_gemm256<1>,
                      hipFuncAttributeMaxDynamicSharedMemorySize, 131072);
  hipFuncSetAttribute((const void*)k_gemm256<2>,
                      hipFuncAttributeMaxDynamicSharedMemorySize, 131072);
  hipFuncSetAttribute((const void*)k_attn,
                      hipFuncAttributeMaxDynamicSharedMemorySize, 74752);

  // 1) hs -> f16
  k_convert<<<8192, 256, 0, stream>>>(hs, hs16);
  // 2) weights -> B^T f16 (rope columns dropped), 128x64 tiles, half8 stores
  k_tc<1><<<dim3(32, 192), 256, 0, stream>>>(wq, wkv, wqkvT);
  // 3) QKV projection GEMM (256^2 8-phase), epilogue scatters Q/K/V^T
  k_gemm256<1><<<768, 512, 131072, stream>>>(hs16, wqkvT, (void*)qkv,
                                             4096, 12288, 4096, 48, 768);
  // 4) wo -> B^T f16 (hs16 slot is dead now)
  k_tc<0><<<dim3(32, 64), 256, 0, stream>>>(wo, nullptr, woT);
  // 5) causal flash attention -> attn [t][4096] f16 (wqkvT slot is dead now)
  k_attn<<<2048, 256, 74752, stream>>>(qkv, qkv + 16777216, qkv + 33554432, attn);
  // 6) output projection (256^2 8-phase) -> fp32 d_out
  k_gemm256<2><<<256, 512, 131072, stream>>>(attn, woT, d_out,
                                             4096, 4096, 4096, 16, 256);
}